// Round 17
// baseline (255.312 us; speedup 1.0000x reference)
//
#include <hip/hip_runtime.h>

#define N_ATOMS 10000
#define N_EDGES 160000
#define N_STRUCT 8
#define D_PAD 48             // max slots per atom; P(Poisson(16) > 48) ~ 2e-7 overall
#define EDW 32               // floats per slot: [0..15]=sh, [16..31]=R (h gathered live)
#define N_SLOTS (N_ATOMS * D_PAD)
#define B4 4                 // slots per register batch
#define PI_F 3.14159265358979323846f
#define SROW 260             // padded LDS row stride (floats)

// ---------------- setup: cursor + accum + h0 + both W transposes (1 dispatch) ----------------

__global__ void setup_kernel(const float* __restrict__ embed, const int* __restrict__ species,
                             const float* __restrict__ Wi1, const float* __restrict__ Wi2,
                             float* __restrict__ h0, float* __restrict__ WT1,
                             float* __restrict__ WT2,
                             int* __restrict__ cursor, float* __restrict__ accum) {
    int i = blockIdx.x * blockDim.x + threadIdx.x;
    if (i < N_ATOMS) cursor[i] = i * D_PAD;
    if (i < N_STRUCT) accum[i] = 0.f;
    if (i < N_ATOMS * 16) {
        int a = i >> 4, c = i & 15;
        h0[i] = embed[species[a] * 16 + c];
    }
    if (i < 4096) {
        int k = i >> 4, c = i & 15;
        WT1[c * 256 + k] = Wi1[i];
        WT2[c * 256 + k] = Wi2[i];
    }
}

// ---------------- scatter + edge geometry FUSED (perm inline; no pad pass) ----------------
// p = atomicAdd gives this edge's slot directly; geometry written in the same
// thread. Pad slots are never written: mp_fused clamps tail indices instead.
// Trig diet (R16-proven): ONE __sincosf + Chebyshev recurrence for all 8 Bessel
// harmonics; fc from the same cosine.

__global__ void scatter_geom(const float* __restrict__ pos, const float* __restrict__ W_rad,
                             const int* __restrict__ senders, const int* __restrict__ receivers,
                             int* __restrict__ cursor,
                             float* __restrict__ edat, int* __restrict__ snd) {
    int e = blockIdx.x * blockDim.x + threadIdx.x;
    if (e >= N_EDGES) return;
    int s = senders[e], rc = receivers[e];
    int p = atomicAdd(&cursor[rc], 1);
    if (p >= (rc + 1) * D_PAD) return;           // >48 edges on one atom: drop (P~2e-7)
    float dx = pos[rc * 3 + 0] - pos[s * 3 + 0];
    float dy = pos[rc * 3 + 1] - pos[s * 3 + 1];
    float dz = pos[rc * 3 + 2] - pos[s * 3 + 2];
    float r = sqrtf(dx * dx + dy * dy + dz * dz);
    float rr = fmaxf(r, 1e-6f);
    float inv = 1.0f / rr;
    float x = dx * inv, y = dy * inv, z = dz * inv;
    float x2 = x * x, y2 = y * y, z2 = z * z;
    float she[16];
    she[0]  = 0.28209479f;
    she[1]  = 0.48860251f * y;
    she[2]  = 0.48860251f * z;
    she[3]  = 0.48860251f * x;
    she[4]  = 1.09254843f * x * y;
    she[5]  = 1.09254843f * y * z;
    she[6]  = 0.31539157f * (3.0f * z2 - 1.0f);
    she[7]  = 1.09254843f * x * z;
    she[8]  = 0.54627422f * (x2 - y2);
    she[9]  = 0.59004359f * y * (3.0f * x2 - y2);
    she[10] = 2.89061144f * x * y * z;
    she[11] = 0.45704579f * y * (5.0f * z2 - 1.0f);
    she[12] = 0.37317633f * z * (5.0f * z2 - 3.0f);
    she[13] = 0.45704579f * x * (5.0f * z2 - 1.0f);
    she[14] = 1.44530572f * z * (x2 - y2);
    she[15] = 0.59004359f * x * (x2 - 3.0f * y2);
    float* ed = edat + (size_t)p * EDW;
    ((float4*)ed)[0] = make_float4(she[0], she[1], she[2], she[3]);
    ((float4*)ed)[1] = make_float4(she[4], she[5], she[6], she[7]);
    ((float4*)ed)[2] = make_float4(she[8], she[9], she[10], she[11]);
    ((float4*)ed)[3] = make_float4(she[12], she[13], she[14], she[15]);

    float theta = PI_F * rr * 0.2f;
    float s1, c1;
    __sincosf(theta, &s1, &c1);
    float fc = (r * 0.2f < 1.0f) ? 0.5f * (c1 + 1.0f) : 0.0f;
    const float kf = 0.6324555320336759f * inv * fc;   // sqrt(2/5)/r * fc
    float bfv[8];
    float sprev = 0.f, scur = s1;
    bfv[0] = kf * scur;
    const float twoc = 2.0f * c1;
    #pragma unroll
    for (int n = 1; n < 8; ++n) {
        float snext = fmaf(twoc, scur, -sprev);    // sin((n+1)t) = 2cos t sin(nt) - sin((n-1)t)
        sprev = scur; scur = snext;
        bfv[n] = kf * scur;
    }

    float Re[16];
    #pragma unroll
    for (int l = 0; l < 4; ++l) {
        #pragma unroll
        for (int n = 0; n < 4; ++n) {
            float acc = 0.0f;
            #pragma unroll
            for (int b = 0; b < 8; ++b) acc = fmaf(bfv[b], W_rad[l * 32 + b * 4 + n], acc);
            Re[l * 4 + n] = acc;
        }
    }
    ((float4*)ed)[4] = make_float4(Re[0], Re[1], Re[2], Re[3]);
    ((float4*)ed)[5] = make_float4(Re[4], Re[5], Re[6], Re[7]);
    ((float4*)ed)[6] = make_float4(Re[8], Re[9], Re[10], Re[11]);
    ((float4*)ed)[7] = make_float4(Re[12], Re[13], Re[14], Re[15]);
    snd[p] = s;
}

// ---------------- MP stage 1: accum + live h gather + inv / energy (fused) --------------
// R15/16's proven loop with tail handling by CLAMP+MASK: invalid tail slots load
// from slot cnt-1 (real, finite) and only shv is zeroed -> contribution is exactly
// 0, no NaN path, no pad pre-zeroing needed. do_energy=1 fuses the w_out dot +
// wave reduce + one atomicAdd (R11's proven energy idiom) -- no Inv round-trip.

__global__ __launch_bounds__(64, 7) void mp_fused(
    const float* __restrict__ edat, const int* __restrict__ snd,
    const int* __restrict__ cursor, const float* __restrict__ h_in,
    float* __restrict__ Inv,
    const float* __restrict__ w_out, const float* __restrict__ comp_w,
    const int* __restrict__ species, const int* __restrict__ sids,
    float* __restrict__ accum, int do_energy)
{
    __shared__ __attribute__((aligned(16))) float wl[1024];   // squares [m*64 + k]
    const int lane = threadIdx.x;                  // block = 1 wave = 1 atom
    const int atom = blockIdx.x;                   // 10000 blocks
    const int m = lane >> 2, cg = lane & 3;
    const int l = (m >= 9) ? 3 : (m >= 4) ? 2 : (m >= 1) ? 1 : 0;
    const int l4 = l * 4, cg4 = cg * 4;

    int cnt = cursor[atom] - atom * D_PAD;
    if (cnt > D_PAD) cnt = D_PAD;
    const int nb = (cnt + B4 - 1) / B4;

    int sv = 0;
    if (lane < D_PAD) sv = snd[atom * D_PAD + lane];

    const float* strip = edat + (size_t)atom * (D_PAD * EDW);

    float acc[4][4];  // [n][j] ; A[m][n*16 + cg*4+j]
    #pragma unroll
    for (int n = 0; n < 4; ++n)
        #pragma unroll
        for (int j = 0; j < 4; ++j) acc[n][j] = 0.f;

    for (int b = 0; b < nb; ++b) {
        const int s0 = b * B4;
        float  shv[B4];
        float4 rv[B4];
        float4 hv[B4];
        #pragma unroll
        for (int q = 0; q < B4; ++q) {
            int sq = s0 + q;
            const bool valid = sq < cnt;
            sq = valid ? sq : (cnt - 1);           // clamp to a real slot (finite data)
            const float* eq = strip + sq * EDW;
            float sh = eq[m];
            shv[q] = valid ? sh : 0.f;             // zero weight kills tail contribution
            rv[q]  = *(const float4*)(eq + 16 + l4);
            hv[q]  = *(const float4*)(h_in + (size_t)__shfl(sv, sq) * 16 + cg4);
        }
        #pragma unroll
        for (int q = 0; q < B4; ++q) {
            float hvj[4] = {hv[q].x, hv[q].y, hv[q].z, hv[q].w};
            float rvn[4] = {rv[q].x, rv[q].y, rv[q].z, rv[q].w};
            #pragma unroll
            for (int j = 0; j < 4; ++j) {
                float ww = shv[q] * hvj[j];
                #pragma unroll
                for (int n = 0; n < 4; ++n)
                    acc[n][j] = fmaf(ww, rvn[n], acc[n][j]);
            }
        }
    }

    // squares -> LDS (same-wave DS is in-order; k = n*16+c in [0,64))
    #pragma unroll
    for (int n = 0; n < 4; ++n)
        *(float4*)&wl[m * 64 + n * 16 + cg4] =
            make_float4(acc[n][0] * acc[n][0], acc[n][1] * acc[n][1],
                        acc[n][2] * acc[n][2], acc[n][3] * acc[n][3]);

    // STATIC column sums (proven idiom): lane = k
    const float* T = wl;
    const int k = lane;
    float s0v = T[k];
    float s1v = T[64 + k] + T[128 + k] + T[192 + k];
    float s2v = T[256 + k] + T[320 + k] + T[384 + k] + T[448 + k] + T[512 + k];
    float s3v = T[576 + k] + T[640 + k] + T[704 + k] + T[768 + k]
              + T[832 + k] + T[896 + k] + T[960 + k];
    const float i0 = s0v;
    const float i1 = s1v * 0.57735026918962576f;
    const float i2 = s2v * 0.44721359549995794f;
    const float i3 = s3v * 0.37796447300922720f;

    if (do_energy) {
        float pe = i0 * w_out[k] + i1 * w_out[64 + k]
                 + i2 * w_out[128 + k] + i3 * w_out[192 + k];
        #pragma unroll
        for (int off = 32; off > 0; off >>= 1) pe += __shfl_down(pe, off);
        if (lane == 0) atomicAdd(&accum[sids[atom]], pe + comp_w[species[atom]]);
    } else {
        float* ip = Inv + (size_t)atom * 256;
        ip[k]       = i0;
        ip[64 + k]  = i1;
        ip[128 + k] = i2;
        ip[192 + k] = i3;
    }
}

// ---------------- MP stage 2 (layer-1 h path only): dense LDS GEMM (proven) ----------------

__global__ __launch_bounds__(256, 2) void mp_inv3h(
    const float* __restrict__ Inv,
    const float* __restrict__ W_invT,
    const float* __restrict__ cemb, float* __restrict__ h_out)
{
    __shared__ __attribute__((aligned(16))) float sWT[16 * SROW];
    __shared__ __attribute__((aligned(16))) float sInv[16 * SROW];
    const int t = threadIdx.x;
    const int blk = blockIdx.x;                    // 625 blocks x 16 atoms

    #pragma unroll
    for (int i = 0; i < 16; ++i) {                 // coalesced loads -> LDS
        int idx = i * 256 + t;
        int row = idx >> 8, col = idx & 255;
        sWT[row * SROW + col]  = W_invT[idx];
        sInv[row * SROW + col] = Inv[(size_t)blk * 4096 + idx];
    }
    __syncthreads();
    // h[a][c] = (sum_k inv[a][k] * W[k][c]) * cemb : LDS-broadcast GEMM
    const int aL = t >> 4, c = t & 15;
    const float* ivp = &sInv[aL * SROW];
    const float* wvp = &sWT[c * SROW];
    float p = 0.f;
    #pragma unroll
    for (int kk = 0; kk < 64; ++kk) {
        float4 iv = *(const float4*)&ivp[kk * 4];
        float4 wv = *(const float4*)&wvp[kk * 4];
        p = fmaf(iv.x, wv.x, p);
        p = fmaf(iv.y, wv.y, p);
        p = fmaf(iv.z, wv.z, p);
        p = fmaf(iv.w, wv.w, p);
    }
    const int gi = blk * 256 + t;                  // = atom*16 + c : full-line store
    h_out[gi] = p * cemb[gi];
}

__global__ void out_kernel(const float* __restrict__ accum, float* __restrict__ out) {
    int t = threadIdx.x;
    if (t < N_STRUCT) out[t] = accum[t];
}

// ---------------- launch (6 dispatches) ----------------

extern "C" void kernel_launch(void* const* d_in, const int* in_sizes, int n_in,
                              void* d_out, int out_size, void* d_ws, size_t ws_size,
                              hipStream_t stream) {
    const float* positions = (const float*)d_in[0];
    const float* embed     = (const float*)d_in[1];
    const float* W_rad     = (const float*)d_in[2];
    const float* W_inv1    = (const float*)d_in[3];
    const float* W_inv2    = (const float*)d_in[4];
    const float* w_out     = (const float*)d_in[5];
    const float* comp_w    = (const float*)d_in[6];
    const int* senders    = (const int*)d_in[7];
    const int* receivers  = (const int*)d_in[8];
    const int* species    = (const int*)d_in[9];
    const int* sids       = (const int*)d_in[10];
    float* out = (float*)d_out;

    char* ws = (char*)d_ws;
    size_t off = 0;
    auto alloc = [&](size_t bytes) -> void* {
        void* p = ws + off;
        off = (off + bytes + 255) & ~(size_t)255;
        return p;
    };
    float* edat     = (float*)alloc((size_t)N_SLOTS * EDW * 4);     // 61.4 MB
    float* Inv      = (float*)alloc((size_t)N_ATOMS * 256 * 4);     // 10.24 MB
    float* h0       = (float*)alloc((size_t)N_ATOMS * 16 * 4);
    float* h1       = (float*)alloc((size_t)N_ATOMS * 16 * 4);
    int*   cursor   = (int*)alloc((size_t)N_ATOMS * 4);
    float* accum    = (float*)alloc(8 * 4);
    float* WT1      = (float*)alloc(4096 * 4);
    float* WT2      = (float*)alloc(4096 * 4);
    int*   snd      = (int*)alloc((size_t)N_SLOTS * 4);

    const int EB = (N_EDGES + 255) / 256;            // 625

    setup_kernel<<<EB, 256, 0, stream>>>(embed, species, W_inv1, W_inv2,
                                         h0, WT1, WT2, cursor, accum);
    scatter_geom<<<EB, 256, 0, stream>>>(positions, W_rad, senders, receivers,
                                         cursor, edat, snd);

    // layer 1 (h gathered live from h0) -> Inv -> h1
    mp_fused<<<N_ATOMS, 64, 0, stream>>>(edat, snd, cursor, h0, Inv,
                                         w_out, comp_w, species, sids, nullptr, 0);
    mp_inv3h<<<N_ATOMS / 16, 256, 0, stream>>>(Inv, WT1, h0, h1);

    // layer 2 (h gathered live from h1) -> energy (fused, no Inv round-trip)
    mp_fused<<<N_ATOMS, 64, 0, stream>>>(edat, snd, cursor, h1, Inv,
                                         w_out, comp_w, species, sids, accum, 1);

    out_kernel<<<1, 64, 0, stream>>>(accum, out);
}

// Round 18
// 157.975 us; speedup vs baseline: 1.6162x; 1.6162x over previous
//
#include <hip/hip_runtime.h>

#define N_ATOMS 10000
#define N_EDGES 160000
#define N_STRUCT 8
#define D_PAD 48             // max slots per atom; P(Poisson(16) > 48) ~ 2e-7 overall
#define EDW 32               // floats per slot: [0..15]=sh, [16..31]=R (h gathered live)
#define N_SLOTS (N_ATOMS * D_PAD)
#define B4 4                 // slots per register batch
#define PI_F 3.14159265358979323846f
#define SROW 260             // padded LDS row stride (floats)

// ---------------- setup: cursor + accum + h0 + both W transposes (1 dispatch) ----------------

__global__ void setup_kernel(const float* __restrict__ embed, const int* __restrict__ species,
                             const float* __restrict__ Wi1, const float* __restrict__ Wi2,
                             float* __restrict__ h0, float* __restrict__ WT1,
                             float* __restrict__ WT2,
                             int* __restrict__ cursor, float* __restrict__ accum) {
    int i = blockIdx.x * blockDim.x + threadIdx.x;
    if (i < N_ATOMS) cursor[i] = i * D_PAD;
    if (i < N_STRUCT) accum[i] = 0.f;
    if (i < N_ATOMS * 16) {
        int a = i >> 4, c = i & 15;
        h0[i] = embed[species[a] * 16 + c];
    }
    if (i < 4096) {
        int k = i >> 4, c = i & 15;
        WT1[c * 256 + k] = Wi1[i];
        WT2[c * 256 + k] = Wi2[i];
    }
}

// ---------------- scatter + edge geometry fused (R17's producer: proven correct) ----------
// p = atomicAdd gives this edge's slot inline; kills the perm round-trip.
// Trig diet (R16-proven): ONE __sincosf + Chebyshev recurrence.

__global__ void scatter_geom(const float* __restrict__ pos, const float* __restrict__ W_rad,
                             const int* __restrict__ senders, const int* __restrict__ receivers,
                             int* __restrict__ cursor,
                             float* __restrict__ edat, int* __restrict__ snd) {
    int e = blockIdx.x * blockDim.x + threadIdx.x;
    if (e >= N_EDGES) return;
    int s = senders[e], rc = receivers[e];
    int p = atomicAdd(&cursor[rc], 1);
    if (p >= (rc + 1) * D_PAD) return;           // >48 edges on one atom: drop (P~2e-7)
    float dx = pos[rc * 3 + 0] - pos[s * 3 + 0];
    float dy = pos[rc * 3 + 1] - pos[s * 3 + 1];
    float dz = pos[rc * 3 + 2] - pos[s * 3 + 2];
    float r = sqrtf(dx * dx + dy * dy + dz * dz);
    float rr = fmaxf(r, 1e-6f);
    float inv = 1.0f / rr;
    float x = dx * inv, y = dy * inv, z = dz * inv;
    float x2 = x * x, y2 = y * y, z2 = z * z;
    float she[16];
    she[0]  = 0.28209479f;
    she[1]  = 0.48860251f * y;
    she[2]  = 0.48860251f * z;
    she[3]  = 0.48860251f * x;
    she[4]  = 1.09254843f * x * y;
    she[5]  = 1.09254843f * y * z;
    she[6]  = 0.31539157f * (3.0f * z2 - 1.0f);
    she[7]  = 1.09254843f * x * z;
    she[8]  = 0.54627422f * (x2 - y2);
    she[9]  = 0.59004359f * y * (3.0f * x2 - y2);
    she[10] = 2.89061144f * x * y * z;
    she[11] = 0.45704579f * y * (5.0f * z2 - 1.0f);
    she[12] = 0.37317633f * z * (5.0f * z2 - 3.0f);
    she[13] = 0.45704579f * x * (5.0f * z2 - 1.0f);
    she[14] = 1.44530572f * z * (x2 - y2);
    she[15] = 0.59004359f * x * (x2 - 3.0f * y2);
    float* ed = edat + (size_t)p * EDW;
    ((float4*)ed)[0] = make_float4(she[0], she[1], she[2], she[3]);
    ((float4*)ed)[1] = make_float4(she[4], she[5], she[6], she[7]);
    ((float4*)ed)[2] = make_float4(she[8], she[9], she[10], she[11]);
    ((float4*)ed)[3] = make_float4(she[12], she[13], she[14], she[15]);

    float theta = PI_F * rr * 0.2f;
    float s1, c1;
    __sincosf(theta, &s1, &c1);
    float fc = (r * 0.2f < 1.0f) ? 0.5f * (c1 + 1.0f) : 0.0f;
    const float kf = 0.6324555320336759f * inv * fc;   // sqrt(2/5)/r * fc
    float bfv[8];
    float sprev = 0.f, scur = s1;
    bfv[0] = kf * scur;
    const float twoc = 2.0f * c1;
    #pragma unroll
    for (int n = 1; n < 8; ++n) {
        float snext = fmaf(twoc, scur, -sprev);    // sin((n+1)t) = 2cos t sin(nt) - sin((n-1)t)
        sprev = scur; scur = snext;
        bfv[n] = kf * scur;
    }

    float Re[16];
    #pragma unroll
    for (int l = 0; l < 4; ++l) {
        #pragma unroll
        for (int n = 0; n < 4; ++n) {
            float acc = 0.0f;
            #pragma unroll
            for (int b = 0; b < 8; ++b) acc = fmaf(bfv[b], W_rad[l * 32 + b * 4 + n], acc);
            Re[l * 4 + n] = acc;
        }
    }
    ((float4*)ed)[4] = make_float4(Re[0], Re[1], Re[2], Re[3]);
    ((float4*)ed)[5] = make_float4(Re[4], Re[5], Re[6], Re[7]);
    ((float4*)ed)[6] = make_float4(Re[8], Re[9], Re[10], Re[11]);
    ((float4*)ed)[7] = make_float4(Re[12], Re[13], Re[14], Re[15]);
    snd[p] = s;
}

// zero ONLY the pad slots [cnt, ceil4(cnt)) + their snd (runs AFTER scatter_geom;
// R15-proven). Restores the unconditional-load contract for mp_accum2.
__global__ void pad_kernel(const int* __restrict__ cursor, float* __restrict__ edat,
                           int* __restrict__ snd) {
    int i = blockIdx.x * blockDim.x + threadIdx.x;
    if (i >= N_ATOMS * 3) return;
    int a = i / 3, j = i % 3;
    int cnt = cursor[a] - a * D_PAD;
    if (cnt > D_PAD) cnt = D_PAD;
    int c4 = (cnt + B4 - 1) / B4 * B4;
    if (c4 > D_PAD) c4 = D_PAD;
    int slot = cnt + j;
    if (slot < c4) {
        float4 z = make_float4(0.f, 0.f, 0.f, 0.f);
        float4* p = (float4*)(edat + (size_t)(a * D_PAD + slot) * EDW);
        #pragma unroll
        for (int k = 0; k < 8; ++k) p[k] = z;
        snd[a * D_PAD + slot] = 0;
    }
}

// ---------------- MP stage 1: accum + live h gather + inv (R16 passing, BYTE-IDENTICAL) ----

__global__ __launch_bounds__(64, 7) void mp_accum2(
    const float* __restrict__ edat, const int* __restrict__ snd,
    const int* __restrict__ cursor, const float* __restrict__ h_in,
    float* __restrict__ Inv)
{
    __shared__ __attribute__((aligned(16))) float wl[1024];   // squares [m*64 + k]
    const int lane = threadIdx.x;                  // block = 1 wave = 1 atom
    const int atom = blockIdx.x;                   // 10000 blocks
    const int m = lane >> 2, cg = lane & 3;
    const int l = (m >= 9) ? 3 : (m >= 4) ? 2 : (m >= 1) ? 1 : 0;
    const int l4 = l * 4, cg4 = cg * 4;

    int cnt = cursor[atom] - atom * D_PAD;
    if (cnt > D_PAD) cnt = D_PAD;
    const int nb = (cnt + B4 - 1) / B4;            // real 4-slot batches (pads zeroed)

    int sv = 0;
    if (lane < D_PAD) sv = snd[atom * D_PAD + lane];

    const float* strip = edat + (size_t)atom * (D_PAD * EDW);

    float acc[4][4];  // [n][j] ; A[m][n*16 + cg*4+j]
    #pragma unroll
    for (int n = 0; n < 4; ++n)
        #pragma unroll
        for (int j = 0; j < 4; ++j) acc[n][j] = 0.f;

    for (int b = 0; b < nb; ++b) {
        const int s0 = b * B4;
        const float* bp = strip + s0 * EDW;
        float  shv[B4];
        float4 rv[B4];
        float4 hv[B4];
        #pragma unroll
        for (int q = 0; q < B4; ++q) {
            const float* eq = bp + q * EDW;
            shv[q] = eq[m];
            rv[q]  = *(const float4*)(eq + 16 + l4);
            hv[q]  = *(const float4*)(h_in + (size_t)__shfl(sv, s0 + q) * 16 + cg4);
        }
        #pragma unroll
        for (int q = 0; q < B4; ++q) {
            float hvj[4] = {hv[q].x, hv[q].y, hv[q].z, hv[q].w};
            float rvn[4] = {rv[q].x, rv[q].y, rv[q].z, rv[q].w};
            #pragma unroll
            for (int j = 0; j < 4; ++j) {
                float ww = shv[q] * hvj[j];
                #pragma unroll
                for (int n = 0; n < 4; ++n)
                    acc[n][j] = fmaf(ww, rvn[n], acc[n][j]);
            }
        }
    }

    // squares -> LDS (same-wave DS is in-order; k = n*16+c in [0,64))
    #pragma unroll
    for (int n = 0; n < 4; ++n)
        *(float4*)&wl[m * 64 + n * 16 + cg4] =
            make_float4(acc[n][0] * acc[n][0], acc[n][1] * acc[n][1],
                        acc[n][2] * acc[n][2], acc[n][3] * acc[n][3]);

    // STATIC column sums (proven idiom): lane = k
    const float* T = wl;
    const int k = lane;
    float s0v = T[k];
    float s1v = T[64 + k] + T[128 + k] + T[192 + k];
    float s2v = T[256 + k] + T[320 + k] + T[384 + k] + T[448 + k] + T[512 + k];
    float s3v = T[576 + k] + T[640 + k] + T[704 + k] + T[768 + k]
              + T[832 + k] + T[896 + k] + T[960 + k];
    float* ip = Inv + (size_t)atom * 256;
    ip[k]       = s0v;
    ip[64 + k]  = s1v * 0.57735026918962576f;
    ip[128 + k] = s2v * 0.44721359549995794f;
    ip[192 + k] = s3v * 0.37796447300922720f;
}

// ---------------- MP stage 2: h / energy from inv (R16 passing, BYTE-IDENTICAL) ----------------

__global__ __launch_bounds__(256, 2) void mp_inv3(
    const float* __restrict__ Inv,
    const float* __restrict__ W_invT,
    const float* __restrict__ cemb, float* __restrict__ h_out,
    const float* __restrict__ w_out, const float* __restrict__ comp_w,
    const int* __restrict__ species, const int* __restrict__ sids,
    float* __restrict__ accum, int do_energy)
{
    __shared__ __attribute__((aligned(16))) float sWT[16 * SROW];
    __shared__ __attribute__((aligned(16))) float sInv[16 * SROW];
    __shared__ float sE[16];
    const int t = threadIdx.x;
    const int w = t >> 6, lane = t & 63;
    const int blk = blockIdx.x;                    // 625 blocks x 16 atoms

    if (do_energy) {
        #pragma unroll
        for (int g = 0; g < 4; ++g) {
            const int atomL = g * 4 + w;
            const size_t base = (size_t)(blk * 16 + atomL) * 256;
            float i0 = Inv[base + lane];
            float i1 = Inv[base + 64 + lane];
            float i2 = Inv[base + 128 + lane];
            float i3 = Inv[base + 192 + lane];
            float pe = i0 * w_out[lane] + i1 * w_out[64 + lane]
                     + i2 * w_out[128 + lane] + i3 * w_out[192 + lane];
            #pragma unroll
            for (int off = 32; off > 0; off >>= 1) pe += __shfl_down(pe, off);
            if (lane == 0) sE[atomL] = pe;
        }
        __syncthreads();
        if (t == 0) {                              // run-compressed atomics (sids sorted)
            const int base = blk * 16;
            int cursid = sids[base];
            float run = 0.f;
            for (int a = 0; a < 16; ++a) {
                int sid = sids[base + a];
                float e = sE[a] + comp_w[species[base + a]];
                if (sid != cursid) { atomicAdd(&accum[cursid], run); run = 0.f; cursid = sid; }
                run += e;
            }
            atomicAdd(&accum[cursid], run);
        }
    } else {
        #pragma unroll
        for (int i = 0; i < 16; ++i) {             // coalesced loads -> LDS
            int idx = i * 256 + t;
            int row = idx >> 8, col = idx & 255;
            sWT[row * SROW + col]  = W_invT[idx];
            sInv[row * SROW + col] = Inv[(size_t)blk * 4096 + idx];
        }
        __syncthreads();
        // h[a][c] = (sum_k inv[a][k] * W[k][c]) * cemb : LDS-broadcast GEMM
        const int aL = t >> 4, c = t & 15;
        const float* ivp = &sInv[aL * SROW];
        const float* wvp = &sWT[c * SROW];
        float p = 0.f;
        #pragma unroll
        for (int kk = 0; kk < 64; ++kk) {
            float4 iv = *(const float4*)&ivp[kk * 4];
            float4 wv = *(const float4*)&wvp[kk * 4];
            p = fmaf(iv.x, wv.x, p);
            p = fmaf(iv.y, wv.y, p);
            p = fmaf(iv.z, wv.z, p);
            p = fmaf(iv.w, wv.w, p);
        }
        const int gi = blk * 256 + t;              // = atom*16 + c : full-line store
        h_out[gi] = p * cemb[gi];
    }
}

__global__ void out_kernel(const float* __restrict__ accum, float* __restrict__ out) {
    int t = threadIdx.x;
    if (t < N_STRUCT) out[t] = accum[t];
}

// ---------------- launch (8 dispatches; perm round-trip eliminated) ----------------

extern "C" void kernel_launch(void* const* d_in, const int* in_sizes, int n_in,
                              void* d_out, int out_size, void* d_ws, size_t ws_size,
                              hipStream_t stream) {
    const float* positions = (const float*)d_in[0];
    const float* embed     = (const float*)d_in[1];
    const float* W_rad     = (const float*)d_in[2];
    const float* W_inv1    = (const float*)d_in[3];
    const float* W_inv2    = (const float*)d_in[4];
    const float* w_out     = (const float*)d_in[5];
    const float* comp_w    = (const float*)d_in[6];
    const int* senders    = (const int*)d_in[7];
    const int* receivers  = (const int*)d_in[8];
    const int* species    = (const int*)d_in[9];
    const int* sids       = (const int*)d_in[10];
    float* out = (float*)d_out;

    char* ws = (char*)d_ws;
    size_t off = 0;
    auto alloc = [&](size_t bytes) -> void* {
        void* p = ws + off;
        off = (off + bytes + 255) & ~(size_t)255;
        return p;
    };
    float* edat     = (float*)alloc((size_t)N_SLOTS * EDW * 4);     // 61.4 MB
    float* Inv      = (float*)alloc((size_t)N_ATOMS * 256 * 4);     // 10.24 MB
    float* h0       = (float*)alloc((size_t)N_ATOMS * 16 * 4);
    float* h1       = (float*)alloc((size_t)N_ATOMS * 16 * 4);
    int*   cursor   = (int*)alloc((size_t)N_ATOMS * 4);
    float* accum    = (float*)alloc(8 * 4);
    float* WT1      = (float*)alloc(4096 * 4);
    float* WT2      = (float*)alloc(4096 * 4);
    int*   snd      = (int*)alloc((size_t)N_SLOTS * 4);

    const int EB = (N_EDGES + 255) / 256;            // 625
    const int PB = (N_ATOMS * 3 + 255) / 256;        // 118

    setup_kernel<<<EB, 256, 0, stream>>>(embed, species, W_inv1, W_inv2,
                                         h0, WT1, WT2, cursor, accum);
    scatter_geom<<<EB, 256, 0, stream>>>(positions, W_rad, senders, receivers,
                                         cursor, edat, snd);
    pad_kernel<<<PB, 256, 0, stream>>>(cursor, edat, snd);

    // layer 1 (h gathered live from h0)
    mp_accum2<<<N_ATOMS, 64, 0, stream>>>(edat, snd, cursor, h0, Inv);
    mp_inv3<<<N_ATOMS / 16, 256, 0, stream>>>(Inv, WT1, h0, h1,
                                              w_out, comp_w, species, sids, accum, 0);
    // layer 2 (energy; h gathered live from h1)
    mp_accum2<<<N_ATOMS, 64, 0, stream>>>(edat, snd, cursor, h1, Inv);
    mp_inv3<<<N_ATOMS / 16, 256, 0, stream>>>(Inv, WT2, h0, h1,
                                              w_out, comp_w, species, sids, accum, 1);

    out_kernel<<<1, 64, 0, stream>>>(accum, out);
}